// Round 8
// baseline (344.480 us; speedup 1.0000x reference)
//
#include <hip/hip_runtime.h>

typedef unsigned short u16;
typedef unsigned int u32;
typedef __bf16 bf16x8 __attribute__((ext_vector_type(8)));
typedef float f32x4 __attribute__((ext_vector_type(4)));

#define BB   4
#define TT   1024
#define CDIM 2048
#define NH   16
#define NKV  4
#define HDIM 128

__device__ __forceinline__ float b2f(u16 u) {
    union { u32 i; float f; } x; x.i = ((u32)u) << 16; return x.f;
}
__device__ __forceinline__ u16 f2b(float f) {
    union { float f; u32 i; } x; x.f = f;
    u32 r = (x.i + 0x7fffu + ((x.i >> 16) & 1u)) >> 16;
    return (u16)r;
}
__device__ __forceinline__ void async16(const void* g, void* l) {
    __builtin_amdgcn_global_load_lds((const __attribute__((address_space(1))) void*)g,
                                     (__attribute__((address_space(3))) void*)l, 16, 0, 0);
}

// Inline dtype probe (wave-uniform): even u16s of fp32 = random mantissa halves.
__device__ __forceinline__ bool wave_is_f32(const u16* xp) {
    u16 v = xp[(threadIdx.x & 63) * 2];
    int e = (v >> 7) & 0xFF;
    bool bad = (v != 0) && (e < 90 || e > 160);
    return __popcll(__ballot(bad)) > 16;
}

// ---------------------------------------------------------------------------
// Fused pre-pass: convert x, cos, sin to bf16 + all three weight transposes.
// ---------------------------------------------------------------------------
__global__ __launch_bounds__(256) void pre_k(const void* __restrict__ x,
                                             const void* __restrict__ Wq,
                                             const void* __restrict__ Wkv,
                                             const void* __restrict__ Wo,
                                             u16* __restrict__ xb,
                                             u16* __restrict__ csb,
                                             u16* __restrict__ snb,
                                             u16* __restrict__ WqkvT,
                                             u16* __restrict__ WoT,
                                             const void* __restrict__ cs,
                                             const void* __restrict__ sn) {
    const bool f32m = wave_is_f32((const u16*)x);
    int bid = blockIdx.x;
    if (bid < 8320) {
        const void* src; u16* dst; int i;
        if (bid < 8192)      { src = x;  dst = xb;  i = bid * 256 + threadIdx.x; }
        else if (bid < 8256) { src = cs; dst = csb; i = (bid - 8192) * 256 + threadIdx.x; }
        else                 { src = sn; dst = snb; i = (bid - 8256) * 256 + threadIdx.x; }
        union { u16 u[4]; ushort4 v; } o;
        if (f32m) {
            float4 f = ((const float4*)src)[i];
            o.u[0] = f2b(f.x); o.u[1] = f2b(f.y); o.u[2] = f2b(f.z); o.u[3] = f2b(f.w);
        } else {
            o.v = ((const ushort4*)src)[i];
        }
        ((ushort4*)dst)[i] = o.v;
        return;
    }
    __shared__ alignas(16) u16 tile[64 * 65];
    int t = bid - 8320;
    const void* W; u16* WT; int rows, cols, bx, by;
    if (t < 1024)      { W = Wq;  WT = WqkvT;                    rows = 2048; cols = 2048; bx = t & 31;  by = t >> 5; }
    else if (t < 1536) { int l = t - 1024; W = Wkv; WT = WqkvT + (long)2048 * 2048; rows = 2048; cols = 1024; bx = l & 15; by = l >> 4; }
    else               { int l = t - 1536; W = Wo;  WT = WoT;  rows = 2048; cols = 2048; bx = l & 31;   by = l >> 5; }
    const int r0 = by * 64, c0 = bx * 64;
#pragma unroll
    for (int i = 0; i < 16; i++) {
        int c = threadIdx.x + i * 256;
        int rr = c >> 6, cc = c & 63;
        long idx = (long)(r0 + rr) * cols + c0 + cc;
        tile[rr * 65 + cc] = f32m ? f2b(((const float*)W)[idx]) : ((const u16*)W)[idx];
    }
    __syncthreads();
#pragma unroll
    for (int i = 0; i < 16; i++) {
        int c = threadIdx.x + i * 256;
        int rr = c >> 6, cc = c & 63;
        WT[(long)(c0 + rr) * rows + r0 + cc] = tile[cc * 65 + rr];
    }
}

// ---------------------------------------------------------------------------
// QKV GEMM with fused RoPE epilogue. Waves own 32-row bands x all 128 cols
// (acc[2][8]) so RoPE pairs (d, d+64) = cols nt, nt+4 are in-wave.
// bn<16: Q head -> RoPE -> Qr (B,H,T,HD). bn 16..19: K head -> RoPE -> Kr.
// bn 20..23: V -> raw store to Vraw (B*T, 512).
// ---------------------------------------------------------------------------
__global__ __launch_bounds__(256) void gemm_qkv(const u16* __restrict__ A,
                                                const u16* __restrict__ Bt,
                                                u16* __restrict__ Qr,
                                                u16* __restrict__ Kr,
                                                u16* __restrict__ Vraw,
                                                const u16* __restrict__ csb,
                                                const u16* __restrict__ snb) {
    __shared__ alignas(16) u16 As[128 * 32];
    __shared__ alignas(16) u16 Bs[128 * 32];
    const int tid = threadIdx.x;
    const int w = tid >> 6, lane = tid & 63;
    const int l16 = lane & 15, quad = lane >> 4;
    const int bm = blockIdx.y, bn = blockIdx.x;
    const long arow0 = (long)bm * 128;
    const long brow0 = (long)bn * 128;
    const int srow = lane >> 2;
    const int schunk = lane & 3;
    const int Kd = 2048;

    f32x4 acc[2][8];
#pragma unroll
    for (int i = 0; i < 2; i++)
#pragma unroll
        for (int j = 0; j < 8; j++) acc[i][j] = {0.f, 0.f, 0.f, 0.f};

    for (int k0 = 0; k0 < Kd; k0 += 32) {
        __syncthreads();
#pragma unroll
        for (int j = 0; j < 2; j++) {
            int r0 = w * 32 + j * 16;
            const u16* gA = A + (arow0 + r0 + srow) * Kd + k0 + schunk * 8;
            async16(gA, &As[r0 * 32]);
            const u16* gB = Bt + (brow0 + r0 + srow) * Kd + k0 + schunk * 8;
            async16(gB, &Bs[r0 * 32]);
        }
        __syncthreads();
        bf16x8 af[2], bfr[8];
#pragma unroll
        for (int mt = 0; mt < 2; mt++)
            af[mt] = *(const bf16x8*)&As[(w * 32 + mt * 16 + l16) * 32 + quad * 8];
#pragma unroll
        for (int nt = 0; nt < 8; nt++)
            bfr[nt] = *(const bf16x8*)&Bs[(nt * 16 + l16) * 32 + quad * 8];
#pragma unroll
        for (int mt = 0; mt < 2; mt++)
#pragma unroll
            for (int nt = 0; nt < 8; nt++)
                acc[mt][nt] = __builtin_amdgcn_mfma_f32_16x16x32_bf16(
                    af[mt], bfr[nt], acc[mt][nt], 0, 0, 0);
    }

    if (bn < 20) {
        // RoPE: u1 = col d (nt<4), u2 = col d+64 (nt+4)
        u16* dst = (bn < 16) ? Qr : Kr;
        const int head = (bn < 16) ? bn : (bn - 16);
        const int hmul = (bn < 16) ? 16 : 4;
#pragma unroll
        for (int mt = 0; mt < 2; mt++) {
#pragma unroll
            for (int nt = 0; nt < 4; nt++) {
                int d = nt * 16 + l16;
#pragma unroll
                for (int r = 0; r < 4; r++) {
                    int t = bm * 128 + w * 32 + mt * 16 + quad * 4 + r;
                    int tt = t & 1023, bb = t >> 10;
                    float c = b2f(csb[tt * 64 + d]);
                    float s = b2f(snb[tt * 64 + d]);
                    float u1 = acc[mt][nt][r], u2 = acc[mt][nt + 4][r];
                    long base = ((long)((bb * hmul + head) * 1024 + tt)) * 128;
                    dst[base + d] = f2b(u1 * c - u2 * s);
                    dst[base + d + 64] = f2b(u1 * s + u2 * c);
                }
            }
        }
    } else {
        const int v0 = (bn - 20) * 128;
#pragma unroll
        for (int mt = 0; mt < 2; mt++)
#pragma unroll
            for (int nt = 0; nt < 8; nt++) {
                int col = nt * 16 + l16;
#pragma unroll
                for (int r = 0; r < 4; r++) {
                    int t = bm * 128 + w * 32 + mt * 16 + quad * 4 + r;
                    Vraw[(long)t * 512 + v0 + col] = f2b(acc[mt][nt][r]);
                }
            }
    }
}

// ---------------------------------------------------------------------------
// m97-style bf16 GEMM (output path): C = A * Bt^T; fp32 out iff xprobe fp32.
// ---------------------------------------------------------------------------
__global__ __launch_bounds__(256) void gemm_bt(const u16* __restrict__ A,
                                               const u16* __restrict__ Bt,
                                               void* __restrict__ C,
                                               int M, int N, int Kd,
                                               const u16* __restrict__ xprobe) {
    __shared__ alignas(16) u16 As[128 * 32];
    __shared__ alignas(16) u16 Bs[128 * 32];
    const bool f32m = (xprobe != nullptr) && wave_is_f32(xprobe);
    const int tid = threadIdx.x;
    const int w = tid >> 6, lane = tid & 63;
    const int wm = w >> 1, wn = w & 1;
    const int l16 = lane & 15, quad = lane >> 4;
    const int bm = blockIdx.y, bn = blockIdx.x;
    const long arow0 = (long)bm * 128;
    const long brow0 = (long)bn * 128;
    const int srow = lane >> 2;
    const int schunk = lane & 3;

    f32x4 acc[4][4];
#pragma unroll
    for (int i = 0; i < 4; i++)
#pragma unroll
        for (int j = 0; j < 4; j++) acc[i][j] = {0.f, 0.f, 0.f, 0.f};

    for (int k0 = 0; k0 < Kd; k0 += 32) {
        __syncthreads();
#pragma unroll
        for (int j = 0; j < 2; j++) {
            int r0 = w * 32 + j * 16;
            const u16* gA = A + (arow0 + r0 + srow) * Kd + k0 + schunk * 8;
            async16(gA, &As[r0 * 32]);
            const u16* gB = Bt + (brow0 + r0 + srow) * Kd + k0 + schunk * 8;
            async16(gB, &Bs[r0 * 32]);
        }
        __syncthreads();
        bf16x8 af[4], bfr[4];
#pragma unroll
        for (int mt = 0; mt < 4; mt++)
            af[mt] = *(const bf16x8*)&As[(wm * 64 + mt * 16 + l16) * 32 + quad * 8];
#pragma unroll
        for (int nt = 0; nt < 4; nt++)
            bfr[nt] = *(const bf16x8*)&Bs[(wn * 64 + nt * 16 + l16) * 32 + quad * 8];
#pragma unroll
        for (int mt = 0; mt < 4; mt++)
#pragma unroll
            for (int nt = 0; nt < 4; nt++)
                acc[mt][nt] = __builtin_amdgcn_mfma_f32_16x16x32_bf16(
                    af[mt], bfr[nt], acc[mt][nt], 0, 0, 0);
    }
#pragma unroll
    for (int mt = 0; mt < 4; mt++) {
#pragma unroll
        for (int nt = 0; nt < 4; nt++) {
            int col = bn * 128 + wn * 64 + nt * 16 + l16;
#pragma unroll
            for (int r = 0; r < 4; r++) {
                long row = bm * 128 + wm * 64 + mt * 16 + quad * 4 + r;
                if (f32m) ((float*)C)[row * N + col] = acc[mt][nt][r];
                else      ((u16*)C)[row * N + col] = f2b(acc[mt][nt][r]);
            }
        }
    }
}

// ---------------------------------------------------------------------------
// V transpose: Vraw (B*T, 512) -> Vt (B,KVH,HD,T).
// ---------------------------------------------------------------------------
__global__ __launch_bounds__(256) void vt2_k(const u16* __restrict__ Vraw,
                                             u16* __restrict__ Vt) {
    __shared__ alignas(16) u16 tile[64 * 65];
    int bid = blockIdx.x;                 // 512 blocks
    int bkv = bid >> 5;                   // b*4+kvh
    int dx = (bid >> 4) & 1, tx = bid & 15;
    int bb = bkv >> 2, kvh = bkv & 3;
#pragma unroll
    for (int i = 0; i < 16; i++) {
        int c = threadIdx.x + i * 256;
        int rr = c >> 6, cc = c & 63;     // rr = t-local, cc = d-local
        tile[rr * 65 + cc] =
            Vraw[((long)(bb * 1024 + tx * 64 + rr)) * 512 + kvh * 128 + dx * 64 + cc];
    }
    __syncthreads();
#pragma unroll
    for (int i = 0; i < 16; i++) {
        int c = threadIdx.x + i * 256;
        int rr = c >> 6, cc = c & 63;     // rr = d-local, cc = t-local
        Vt[((long)bkv * 128 + dx * 64 + rr) * 1024 + tx * 64 + cc] = tile[cc * 65 + rr];
    }
}

// ---------------------------------------------------------------------------
// Flash attention v6: 128 q-rows per block, 32 q per wave (2 halves of 16).
// Every K/V fragment read feeds 2 MFMAs (shared across halves) => LDS-read
// cost per unit work ~halved vs v5. Balanced pairs: block b does items
// {b, 511-b} (qt2 pair (a,7-a)) = exactly 18 k-tile iterations. Grid 256.
// Double-buffered K/V, fine vmcnt, no vmcnt(0) inside the loop.
// ---------------------------------------------------------------------------
__global__ __launch_bounds__(256) void attn_kernel(const u16* __restrict__ Q,
                                                   const u16* __restrict__ Kr,
                                                   const u16* __restrict__ Vt,
                                                   u16* __restrict__ O) {
    __shared__ alignas(16) u16 Ks[2][64 * 128];   // [t][d], chunk ^= row&7 (bit3 kept)
    __shared__ alignas(16) u16 Vts[2][128 * 64];  // [d][t], chunk ^= row&7
    __shared__ alignas(16) u16 Ps[128 * 88];      // [q][k], per-wave rows only

    const int tid = threadIdx.x, w = tid >> 6, lane = tid & 63;
    const int l16 = lane & 15, quad = lane >> 4;
    const float scale2 = 0.08838834764831845f * 1.4426950408889634f; // 1/sqrt(128)*log2e

#pragma unroll 1
    for (int it = 0; it < 2; it++) {
        const int j = it ? (511 - (int)blockIdx.x) : (int)blockIdx.x;
        const int qt2 = 7 - (j >> 6);        // 128-row q tile, heavy first
        const int bh = j & 63;
        const int b = bh >> 4, h = bh & 15;
        const int kvh = h >> 2;
        const int nkt = 2 * qt2 + 2;         // k tiles 0..nkt-1
        const long qrow0 = (long)bh * TT + qt2 * 128;
        const long krow0 = (long)(b * NKV + kvh) * TT;
        const long vbase = ((long)(b * NKV + kvh) * HDIM) * TT;

        __syncthreads();  // prior item fully done with LDS

        // ---- stage this wave's 32 Q rows (rows w*32..w*32+31 across Ks[0/1]) ----
#pragma unroll
        for (int i = 0; i < 8; i++) {
            int grb = w * 32 + i * 4;                 // global row base (0..127)
            int buf = w >> 1;                         // rows<64 -> Ks[0]
            int lrb = grb & 63;
            int gr = grb + (lane >> 4);
            int cp = lane & 15;
            int cg = (cp & 8) | ((cp ^ gr) & 7);
            async16(Q + (qrow0 + gr) * HDIM + cg * 8, &Ks[buf][lrb * 128]);
        }
        asm volatile("s_waitcnt vmcnt(0)" ::: "memory");
        bf16x8 qf[2][4];
#pragma unroll
        for (int hf = 0; hf < 2; hf++) {
            int Rq = (w & 1) * 32 + hf * 16 + l16;    // local row in Ks[w>>1]
#pragma unroll
            for (int ds = 0; ds < 4; ds++) {
                int c = ds * 4 + quad;
                qf[hf][ds] = *(const bf16x8*)&Ks[w >> 1][Rq * 128 + ((c & 8) | ((c ^ Rq) & 7)) * 8];
            }
        }
        __syncthreads();  // all waves own their Q frags before K overwrites

        // ---- prologue: kt0 -> buf0, kt1 -> buf1 (nkt >= 2 always) ----
#pragma unroll
        for (int kt0 = 0; kt0 < 2; kt0++) {
#pragma unroll
            for (int i = 0; i < 4; i++) {
                int slot0 = (w * 4 + i) * 64;
                int slot = slot0 + lane;
                int row = slot >> 4, cp = slot & 15;
                int cg = (cp & 8) | ((cp ^ row) & 7);
                async16(Kr + (krow0 + kt0 * 64 + row) * HDIM + cg * 8, &Ks[kt0][slot0 * 8]);
            }
#pragma unroll
            for (int i = 0; i < 4; i++) {
                int slot0 = (w * 4 + i) * 64;
                int slot = slot0 + lane;
                int row = slot >> 3, cp = slot & 7;
                int cg = cp ^ (row & 7);
                async16(Vt + vbase + (long)row * TT + kt0 * 64 + cg * 8, &Vts[kt0][slot0 * 8]);
            }
        }
        asm volatile("s_waitcnt vmcnt(8)" ::: "memory");
        asm volatile("s_barrier" ::: "memory");

        f32x4 o[2][8];
#pragma unroll
        for (int hf = 0; hf < 2; hf++)
#pragma unroll
            for (int i = 0; i < 8; i++) o[hf][i] = {0.f, 0.f, 0.f, 0.f};
        float m_i[2] = {-1.0e30f, -1.0e30f}, l_i[2] = {0.f, 0.f};
        const int qg0 = qt2 * 128 + w * 32 + l16;

#pragma unroll 1
        for (int kt = 0; kt < nkt; kt++) {
            const int cur = kt & 1;
            const u16* ksb = Ks[cur];
            const u16* vsb = Vts[cur];

            // S^T for both halves; each K fragment feeds 2 MFMAs
            f32x4 s[2][4];
#pragma unroll
            for (int hf = 0; hf < 2; hf++)
#pragma unroll
                for (int nt = 0; nt < 4; nt++) s[hf][nt] = {0.f, 0.f, 0.f, 0.f};
#pragma unroll
            for (int ds = 0; ds < 4; ds++) {
                int c = ds * 4 + quad;
#pragma unroll
                for (int nt = 0; nt < 4; nt++) {
                    int Rk = nt * 16 + l16;
                    bf16x8 ak = *(const bf16x8*)&ksb[Rk * 128 + ((c & 8) | ((c ^ Rk) & 7)) * 8];
                    s[0][nt] = __builtin_amdgcn_mfma_f32_16x16x32_bf16(ak, qf[0][ds], s[0][nt], 0, 0, 0);
                    s[1][nt] = __builtin_amdgcn_mfma_f32_16x16x32_bf16(ak, qf[1][ds], s[1][nt], 0, 0, 0);
                }
            }

            const bool need_mask = (kt >= 2 * qt2);
            float alpha[2];
#pragma unroll
            for (int hf = 0; hf < 2; hf++) {
                const int qg = qg0 + hf * 16;
                float p[4][4];
                float mx = -1.0e30f;
#pragma unroll
                for (int nt = 0; nt < 4; nt++)
#pragma unroll
                    for (int r = 0; r < 4; r++) {
                        float v = (float)s[hf][nt][r] * scale2;
                        if (need_mask) {
                            int kg = kt * 64 + nt * 16 + quad * 4 + r;
                            if (kg > qg) v = -1.0e30f;
                        }
                        p[nt][r] = v;
                        mx = fmaxf(mx, v);
                    }
                mx = fmaxf(mx, __shfl_xor(mx, 16));
                mx = fmaxf(mx, __shfl_xor(mx, 32));
                float mnew = fmaxf(m_i[hf], mx);
                alpha[hf] = exp2f(m_i[hf] - mnew);
                float rs = 0.f;
#pragma unroll
                for (int nt = 0; nt < 4; nt++)
#pragma unroll
                    for (int r = 0; r < 4; r++) {
                        float e = exp2f(p[nt][r] - mnew);
                        p[nt][r] = e;
                        rs += e;
                    }
                rs += __shfl_xor(rs, 16);
                rs += __shfl_xor(rs, 32);
                l_i[hf] = l_i[hf] * alpha[hf] + rs;
                m_i[hf] = mnew;
                // P -> Ps (uint2 packed, own rows)
                u32* Psw = (u32*)Ps;
                int pb = (w * 32 + hf * 16 + l16) * 44 + quad * 2;
#pragma unroll
                for (int nt = 0; nt < 4; nt++) {
                    uint2 pk;
                    pk.x = (u32)f2b(p[nt][0]) | ((u32)f2b(p[nt][1]) << 16);
                    pk.y = (u32)f2b(p[nt][2]) | ((u32)f2b(p[nt][3]) << 16);
                    *(uint2*)&Psw[pb + nt * 8] = pk;
                }
                if (__ballot(alpha[hf] != 1.0f) != 0ULL) {
#pragma unroll
                    for (int n8 = 0; n8 < 8; n8++)
#pragma unroll
                        for (int r = 0; r < 4; r++) o[hf][n8][r] *= alpha[hf];
                }
            }

            asm volatile("s_waitcnt lgkmcnt(0)" ::: "memory");  // Ps W->R, same wave

            // PV: each V fragment feeds 2 MFMAs
#pragma unroll
            for (int ks = 0; ks < 2; ks++) {
                bf16x8 bp0 = *(const bf16x8*)&Ps[(w * 32 + l16) * 88 + ks * 32 + quad * 8];
                bf16x8 bp1 = *(const bf16x8*)&Ps[(w * 32 + 16 + l16) * 88 + ks * 32 + quad * 8];
#pragma unroll
                for (int n8 = 0; n8 < 8; n8++) {
                    int Rv = n8 * 16 + l16;
                    int c = ks * 4 + quad;
                    bf16x8 av = *(const bf16x8*)&vsb[Rv * 64 + (c ^ (Rv & 7)) * 8];
                    o[0][n8] = __builtin_amdgcn_mfma_f32_16x16x32_bf16(av, bp0, o[0][n8], 0, 0, 0);
                    o[1][n8] = __builtin_amdgcn_mfma_f32_16x16x32_bf16(av, bp1, o[1][n8], 0, 0, 0);
                }
            }

            if (kt == nkt - 1) break;

            asm volatile("s_waitcnt lgkmcnt(0)" ::: "memory");
            asm volatile("s_barrier" ::: "memory");   // all waves done with buf[cur]
            if (kt + 2 < nkt) {
                const int nk = kt + 2;
#pragma unroll
                for (int i = 0; i < 4; i++) {
                    int slot0 = (w * 4 + i) * 64;
                    int slot = slot0 + lane;
                    int row = slot >> 4, cp = slot & 15;
                    int cg = (cp & 8) | ((cp ^ row) & 7);
                    async16(Kr + (krow0 + nk * 64 + row) * HDIM + cg * 8, &Ks[cur][slot0 * 8]);
                }
#pragma unroll
                for (int i = 0; i < 4; i++) {
                    int slot0 = (w * 4 + i) * 64;
                    int slot = slot0 + lane;
                    int row = slot >> 3, cp = slot & 7;
                    int cg = cp ^ (row & 7);
                    async16(Vt + vbase + (long)row * TT + nk * 64 + cg * 8, &Vts[cur][slot0 * 8]);
                }
                asm volatile("s_waitcnt vmcnt(8)" ::: "memory");
            } else {
                asm volatile("s_waitcnt vmcnt(0)" ::: "memory");
            }
            asm volatile("s_barrier" ::: "memory");   // buf[1-cur] ready everywhere
        }

        // epilogue: both halves
#pragma unroll
        for (int hf = 0; hf < 2; hf++) {
            float inv = 1.0f / l_i[hf];
            const int qg = qg0 + hf * 16;
            long obase = ((long)(b * TT + qg)) * CDIM + h * HDIM;
#pragma unroll
            for (int n8 = 0; n8 < 8; n8++) {
                ushort4 st;
                st.x = f2b(o[hf][n8][0] * inv);
                st.y = f2b(o[hf][n8][1] * inv);
                st.z = f2b(o[hf][n8][2] * inv);
                st.w = f2b(o[hf][n8][3] * inv);
                *(ushort4*)&O[obase + n8 * 16 + quad * 4] = st;
            }
        }
    }
}

// ---------------------------------------------------------------------------
extern "C" void kernel_launch(void* const* d_in, const int* in_sizes, int n_in,
                              void* d_out, int out_size, void* d_ws, size_t ws_size,
                              hipStream_t stream) {
    const void* x   = d_in[0];
    const void* Wq  = d_in[1];
    const void* Wkv = d_in[2];
    const void* Wo  = d_in[3];
    const void* cs  = d_in[4];
    const void* sn  = d_in[5];

    char* ws = (char*)d_ws;
    const size_t NEED = 84148224;
    if (ws_size < NEED) return;

    u16* WqkvT = (u16*)(ws + 0);          // 3072x2048
    u16* WoT   = (u16*)(ws + 12582912);   // 2048x2048
    u16* Qr    = (u16*)(ws + 20971520);   // (B,H,T,HD) 16MB
    u16* Kr    = (u16*)(ws + 37748736);   // (B,KVH,T,HD) 4MB
    u16* Vraw  = (u16*)(ws + 41943040);   // (B*T,512) 4MB
    u16* Vt    = (u16*)(ws + 46137344);   // (B,KVH,HD,T) 4MB
    u16* ATT   = (u16*)(ws + 50331648);   // 4096x2048 16MB
    u16* xb    = (u16*)(ws + 67108864);   // 4096x2048 16MB
    u16* csb   = (u16*)(ws + 83886080);   // 1024x64
    u16* snb   = (u16*)(ws + 84017152);   // 1024x64

    pre_k<<<10880, 256, 0, stream>>>(x, Wq, Wkv, Wo, xb, csb, snb, WqkvT, WoT, cs, sn);

    gemm_qkv<<<dim3(24, 32), 256, 0, stream>>>(xb, WqkvT, Qr, Kr, Vraw, csb, snb);

    vt2_k<<<512, 256, 0, stream>>>(Vraw, Vt);

    attn_kernel<<<256, 256, 0, stream>>>(Qr, Kr, Vt, ATT);

    gemm_bt<<<dim3(16, 32), 256, 0, stream>>>(ATT, WoT, d_out, 4096, 2048, 2048, (const u16*)x);
}